// Round 6
// baseline (133.776 us; speedup 1.0000x reference)
//
#include <hip/hip_runtime.h>

#define NUM_MOL 1024
#define KEHALF 7.199822675975274f
#define RCUT 10.0f

__device__ __forceinline__ float softplus_f(float x) {
    // log1p(exp(x)); fast path (params are O(1), tolerance allows ~1e-7 rel)
    return (x > 20.0f) ? x : __logf(1.0f + __expf(x));
}

__device__ __forceinline__ float uni(float x) {
    // force uniform value into an SGPR (frees VGPRs, marks uniformity)
    return __int_as_float(__builtin_amdgcn_readfirstlane(__float_as_int(x)));
}

// ===========================================================================
// Prep: once per launch,
//   ws[0..1KB)    : zptab_g[256]  = t^softplus(apow) * softplus(adiv)
//   ws[1KB..+N)   : zu8[N]        = (u8)Z[n]
// The 100KB u8 table is L2-resident (4 MiB/XCD) during the edge kernel.
// ===========================================================================
__global__ __launch_bounds__(256) void zbl_prep(
    const float* __restrict__ Z,
    const float* __restrict__ apow,
    const float* __restrict__ adiv,
    float* __restrict__ zptab_g,
    unsigned char* __restrict__ zu8, int N)
{
    const int n4 = blockIdx.x * blockDim.x + threadIdx.x;   // one float4 per thread
    const int nv4 = N >> 2;
    if (n4 < nv4) {
        const float4 zv = ((const float4*)Z)[n4];
        uchar4 pk;
        pk.x = (unsigned char)(int)zv.x;
        pk.y = (unsigned char)(int)zv.y;
        pk.z = (unsigned char)(int)zv.z;
        pk.w = (unsigned char)(int)zv.w;
        ((uchar4*)zu8)[n4] = pk;
    }
    // scalar tail
    const int base = nv4 << 2;
    if (n4 < N - base) zu8[base + n4] = (unsigned char)(int)Z[base + n4];
    // 256-entry scaled pow LUT (block 0 only)
    if (blockIdx.x == 0 && threadIdx.x < 256) {
        const float p = softplus_f(apow[0]);
        const float s = softplus_f(adiv[0]);
        const int t = threadIdx.x;
        zptab_g[t] = (t > 0) ? __powf((float)t, p) * s : 0.0f;
    }
}

// ===========================================================================
// Primary edge kernel: high-occupancy, 1 KiB LDS (just the LUT).
//   - z via 1-byte gathers from the L2-resident u8 table
//   - z^p*sp(adiv) via 256-float LDS LUT (random reads ~2-way = free)
//   - exact early-out: (si+sj)*d >= C2  =>  all expf args <= -104
//     => exp == 0.0f (below denormal min) => ee == 0 bit-exactly.
//   - survivors (~1%): masked idx_m gather + direct global atomicAdd.
// ===========================================================================
__global__ __launch_bounds__(256, 8) void zbl_edge_l2(
    const float4* __restrict__ r4,
    const int4* __restrict__ idx_i4,
    const int4* __restrict__ idx_j4,
    const int* __restrict__ idx_i,
    const int* __restrict__ idx_j,
    const float* __restrict__ r_ij,
    const unsigned char* __restrict__ zu8,
    const float* __restrict__ zptab_g,
    const int* __restrict__ idx_m,
    const float* __restrict__ a_vector,
    const float* __restrict__ c_vector,
    float* __restrict__ y, int E)
{
    __shared__ float zptab[256];
    zptab[threadIdx.x] = zptab_g[threadIdx.x];          // blockDim == 256

    // ---- uniform scalar parameters -> SGPRs ----
    const float sa0 = uni(softplus_f(a_vector[0]));
    const float sa1 = uni(softplus_f(a_vector[1]));
    const float sa2 = uni(softplus_f(a_vector[2]));
    const float sa3 = uni(softplus_f(a_vector[3]));
    float c0 = softplus_f(c_vector[0]);
    float c1 = softplus_f(c_vector[1]);
    float c2 = softplus_f(c_vector[2]);
    float c3 = softplus_f(c_vector[3]);
    const float cinv = 1.0f / (fabsf(c0) + fabsf(c1) + fabsf(c2) + fabsf(c3));
    const float k0 = uni(c0 * cinv);
    const float k1 = uni(c1 * cinv);
    const float k2 = uni(c2 * cinv);
    const float k3 = uni(c3 * cinv);
    const float samin = fminf(fminf(sa0, sa1), fminf(sa2, sa3));
    const float C2 = uni(104.0f / samin);   // LUT is pre-scaled by sp(adiv)

    __syncthreads();

    auto edge1 = [&](int i, int j, float d2) {
        const int zi = zu8[i];              // global 1B gather, L2-resident
        const int zj = zu8[j];
        const float si = zptab[zi];         // LDS LUT (pre-scaled z^p)
        const float sj = zptab[zj];
        const float d = sqrtf(d2);
        const float ad = (si + sj) * d;     // == (zpi+zpj)*sp_adiv*d
        if (ad < C2) {
            const float rinv = rsqrtf(d2);
            const float u = d * (1.0f / RCUT);
            const float u3 = u * u * u;
            float fc = 1.0f + u3 * (-10.0f + u * (15.0f - 6.0f * u));
            fc = (d < RCUT) ? fc : 0.0f;
            const float ft = k0 * __expf(-sa0 * ad) + k1 * __expf(-sa1 * ad)
                           + k2 * __expf(-sa2 * ad) + k3 * __expf(-sa3 * ad);
            const float ee = KEHALF * ft * fc * (float)(zi * zj) * rinv;
            if (ee != 0.0f) atomicAdd(&y[idx_m[i]], ee);
        }
    };

    const int t = blockIdx.x * blockDim.x + threadIdx.x;
    const int nthr = gridDim.x * blockDim.x;
    const int E4 = E >> 2;

    for (int g = t; g < E4; g += nthr) {
        const int4 vi = idx_i4[g];
        const int4 vj = idx_j4[g];
        const float4 r0 = r4[3 * g + 0];
        const float4 r1 = r4[3 * g + 1];
        const float4 r2 = r4[3 * g + 2];
        edge1(vi.x, vj.x, r0.x * r0.x + r0.y * r0.y + r0.z * r0.z);
        edge1(vi.y, vj.y, r0.w * r0.w + r1.x * r1.x + r1.y * r1.y);
        edge1(vi.z, vj.z, r1.z * r1.z + r1.w * r1.w + r2.x * r2.x);
        edge1(vi.w, vj.w, r2.y * r2.y + r2.z * r2.z + r2.w * r2.w);
    }

    // tail (E % 4 != 0 — not hit for this benchmark but kept for generality)
    for (int e = (E4 << 2) + t; e < E; e += nthr) {
        const float x  = r_ij[3 * e + 0];
        const float yy = r_ij[3 * e + 1];
        const float zz = r_ij[3 * e + 2];
        edge1(idx_i[e], idx_j[e], x * x + yy * yy + zz * zz);
    }
}

// ===========================================================================
// Fallback (no workspace): gather Z/idx_m directly, pow per edge, LDS bins
// ===========================================================================
__global__ __launch_bounds__(256) void zbl_edge_kernel_nows(
    const float* __restrict__ r_ij,
    const int* __restrict__ idx_i,
    const int* __restrict__ idx_j,
    const float* __restrict__ Z,
    const int* __restrict__ idx_m,
    const float* __restrict__ adiv,
    const float* __restrict__ apow,
    const float* __restrict__ a_vector,
    const float* __restrict__ c_vector,
    float* __restrict__ y, int E)
{
    __shared__ float bins[NUM_MOL];
    for (int b = threadIdx.x; b < NUM_MOL; b += blockDim.x) bins[b] = 0.0f;
    __syncthreads();

    const float sp_apow = softplus_f(apow[0]);
    const float sp_adiv = softplus_f(adiv[0]);
    const float sa0 = softplus_f(a_vector[0]);
    const float sa1 = softplus_f(a_vector[1]);
    const float sa2 = softplus_f(a_vector[2]);
    const float sa3 = softplus_f(a_vector[3]);
    float c0 = softplus_f(c_vector[0]);
    float c1 = softplus_f(c_vector[1]);
    float c2 = softplus_f(c_vector[2]);
    float c3 = softplus_f(c_vector[3]);
    const float cs = fabsf(c0) + fabsf(c1) + fabsf(c2) + fabsf(c3);
    const float cinv = 1.0f / cs;
    c0 *= cinv; c1 *= cinv; c2 *= cinv; c3 *= cinv;

    const int stride = gridDim.x * blockDim.x;
    for (int e = blockIdx.x * blockDim.x + threadIdx.x; e < E; e += stride) {
        const int i = idx_i[e];
        const int j = idx_j[e];
        const float zi = Z[i];
        const float zj = Z[j];
        const float x  = r_ij[3 * e + 0];
        const float yy = r_ij[3 * e + 1];
        const float zz = r_ij[3 * e + 2];
        const float d = sqrtf(x * x + yy * yy + zz * zz);

        const float u = d * (1.0f / RCUT);
        const float u3 = u * u * u;
        float fc = 1.0f + u3 * (-10.0f + u * (15.0f - 6.0f * u));
        fc = (d < RCUT) ? fc : 0.0f;

        const float a = (__powf(zi, sp_apow) + __powf(zj, sp_apow)) * sp_adiv;
        const float ad = a * d;
        const float ft = c0 * __expf(-sa0 * ad) + c1 * __expf(-sa1 * ad)
                       + c2 * __expf(-sa2 * ad) + c3 * __expf(-sa3 * ad);

        const float ee = KEHALF * ft * fc * zi * zj / d;
        if (ee != 0.0f) atomicAdd(&bins[idx_m[i]], ee);
    }

    __syncthreads();
    for (int b = threadIdx.x; b < NUM_MOL; b += blockDim.x) {
        const float v = bins[b];
        if (v != 0.0f) atomicAdd(&y[b], v);
    }
}

extern "C" void kernel_launch(void* const* d_in, const int* in_sizes, int n_in,
                              void* d_out, int out_size, void* d_ws, size_t ws_size,
                              hipStream_t stream) {
    // setup_inputs order: Z, r_ij, idx_i, idx_j, idx_m, adiv, apow, a_vector, c_vector
    const float* Z        = (const float*)d_in[0];
    const float* r_ij     = (const float*)d_in[1];
    const int*   idx_i    = (const int*)d_in[2];
    const int*   idx_j    = (const int*)d_in[3];
    const int*   idx_m    = (const int*)d_in[4];
    const float* adiv     = (const float*)d_in[5];
    const float* apow     = (const float*)d_in[6];
    const float* a_vector = (const float*)d_in[7];
    const float* c_vector = (const float*)d_in[8];
    float* y = (float*)d_out;

    const int N = in_sizes[0];
    const int E = in_sizes[1] / 3;

    // d_out is poisoned 0xAA before every launch -> zero it (graph-safe memset node)
    hipMemsetAsync(y, 0, (size_t)out_size * sizeof(float), stream);

    const size_t ws_need = 1024 + (size_t)N + 16;
    if (ws_size >= ws_need) {
        float* zptab_g = (float*)d_ws;
        unsigned char* zu8 = (unsigned char*)d_ws + 1024;
        zbl_prep<<<(N / 4 + 255) / 256 + 1, 256, 0, stream>>>(
            Z, apow, adiv, zptab_g, zu8, N);
        // high-occupancy: 256 threads/block, 1 KiB LDS, target 8 blocks/CU
        zbl_edge_l2<<<2048, 256, 0, stream>>>(
            (const float4*)r_ij, (const int4*)idx_i, (const int4*)idx_j,
            idx_i, idx_j, r_ij, zu8, zptab_g, idx_m,
            a_vector, c_vector, y, E);
    } else {
        zbl_edge_kernel_nows<<<2048, 256, 0, stream>>>(r_ij, idx_i, idx_j, Z, idx_m,
                                                       adiv, apow, a_vector, c_vector, y, E);
    }
}

// Round 7
// 127.148 us; speedup vs baseline: 1.0521x; 1.0521x over previous
//
#include <hip/hip_runtime.h>

#define NUM_MOL 1024
#define KEHALF 7.199822675975274f
#define RCUT 10.0f
// atoms [0, ZS_LDS) are served from LDS; the rest gather from the L2-hot
// u8 table. 64KB slice + 1KB LUT = 65.3KB LDS -> 2 blocks/CU -> 32 waves/CU.
#define ZS_LDS 65536

__device__ __forceinline__ float softplus_f(float x) {
    // log1p(exp(x)); fast path (params are O(1), tolerance allows ~1e-7 rel)
    return (x > 20.0f) ? x : __logf(1.0f + __expf(x));
}

__device__ __forceinline__ float uni(float x) {
    // force uniform value into an SGPR (frees VGPRs, marks uniformity)
    return __int_as_float(__builtin_amdgcn_readfirstlane(__float_as_int(x)));
}

// ===========================================================================
// Prep: once per launch,
//   ws[0..1KB)    : zptab_g[256]  = t^softplus(apow) * softplus(adiv)
//   ws[1KB..+N)   : zu8[N]        = (u8)Z[n]
// ===========================================================================
__global__ __launch_bounds__(256) void zbl_prep(
    const float* __restrict__ Z,
    const float* __restrict__ apow,
    const float* __restrict__ adiv,
    float* __restrict__ zptab_g,
    unsigned char* __restrict__ zu8, int N)
{
    const int n4 = blockIdx.x * blockDim.x + threadIdx.x;   // one float4 per thread
    const int nv4 = N >> 2;
    if (n4 < nv4) {
        const float4 zv = ((const float4*)Z)[n4];
        uchar4 pk;
        pk.x = (unsigned char)(int)zv.x;
        pk.y = (unsigned char)(int)zv.y;
        pk.z = (unsigned char)(int)zv.z;
        pk.w = (unsigned char)(int)zv.w;
        ((uchar4*)zu8)[n4] = pk;
    }
    // scalar tail
    const int base = nv4 << 2;
    if (n4 < N - base) zu8[base + n4] = (unsigned char)(int)Z[base + n4];
    // 256-entry scaled pow LUT (block 0 only)
    if (blockIdx.x == 0 && threadIdx.x < 256) {
        const float p = softplus_f(apow[0]);
        const float s = softplus_f(adiv[0]);
        const int t = threadIdx.x;
        zptab_g[t] = (t > 0) ? __powf((float)t, p) * s : 0.0f;
    }
}

// ===========================================================================
// Primary edge kernel: split z-table.
//   - atoms < ZS_LDS: ds_read_u8 from the 64KB LDS slice (65% of lookups)
//   - atoms >= ZS_LDS: 1B gather from the L2/L1-hot 34KB table slice
//     (~1/3 lane pressure -> ~3x less vmem-gather line traffic than R6)
//   - 2 blocks/CU x 16 waves = 32 waves/CU: full occupancy latency hiding
//   - exact early-out: (si+sj)*d >= C2  =>  all expf args <= -104
//     => exp == 0.0f => ee == 0 bit-exactly.
//   - survivors (~0.3%): masked idx_m gather + direct global atomicAdd.
// ===========================================================================
__global__ __launch_bounds__(1024, 8) void zbl_edge_split(
    const float4* __restrict__ r4,
    const int4* __restrict__ idx_i4,
    const int4* __restrict__ idx_j4,
    const int* __restrict__ idx_i,
    const int* __restrict__ idx_j,
    const float* __restrict__ r_ij,
    const unsigned char* __restrict__ zu8,
    const float* __restrict__ zptab_g,
    const int* __restrict__ idx_m,
    const float* __restrict__ a_vector,
    const float* __restrict__ c_vector,
    float* __restrict__ y, int N, int E)
{
    __shared__ float zptab[256];
    __shared__ unsigned char zs[ZS_LDS];
    const int tid = threadIdx.x;

    // fill LDS slice with raw 16B copies from the prep'd u8 table
    {
        const int nlds = (N < ZS_LDS) ? N : ZS_LDS;
        const int nchunk = (nlds + 15) >> 4;          // ws is 256MiB: tail-read safe
        const uint4* src = (const uint4*)zu8;
        uint4* dst = (uint4*)zs;
        for (int k = tid; k < nchunk; k += blockDim.x) dst[k] = src[k];
    }
    if (tid < 256) zptab[tid] = zptab_g[tid];

    // ---- uniform scalar parameters -> SGPRs ----
    const float sa0 = uni(softplus_f(a_vector[0]));
    const float sa1 = uni(softplus_f(a_vector[1]));
    const float sa2 = uni(softplus_f(a_vector[2]));
    const float sa3 = uni(softplus_f(a_vector[3]));
    float c0 = softplus_f(c_vector[0]);
    float c1 = softplus_f(c_vector[1]);
    float c2 = softplus_f(c_vector[2]);
    float c3 = softplus_f(c_vector[3]);
    const float cinv = 1.0f / (fabsf(c0) + fabsf(c1) + fabsf(c2) + fabsf(c3));
    const float k0 = uni(c0 * cinv);
    const float k1 = uni(c1 * cinv);
    const float k2 = uni(c2 * cinv);
    const float k3 = uni(c3 * cinv);
    const float samin = fminf(fminf(sa0, sa1), fminf(sa2, sa3));
    const float C2 = uni(104.0f / samin);   // LUT is pre-scaled by sp(adiv)

    __syncthreads();

    auto edge1 = [&](int i, int j, float d2) {
        int zi, zj;
        if (i < ZS_LDS) zi = zs[i]; else zi = zu8[i];
        if (j < ZS_LDS) zj = zs[j]; else zj = zu8[j];
        const float si = zptab[zi];         // LDS LUT (pre-scaled z^p)
        const float sj = zptab[zj];
        const float d = sqrtf(d2);
        const float ad = (si + sj) * d;     // == (zpi+zpj)*sp_adiv*d
        if (ad < C2) {
            const float rinv = rsqrtf(d2);
            const float u = d * (1.0f / RCUT);
            const float u3 = u * u * u;
            float fc = 1.0f + u3 * (-10.0f + u * (15.0f - 6.0f * u));
            fc = (d < RCUT) ? fc : 0.0f;
            const float ft = k0 * __expf(-sa0 * ad) + k1 * __expf(-sa1 * ad)
                           + k2 * __expf(-sa2 * ad) + k3 * __expf(-sa3 * ad);
            const float ee = KEHALF * ft * fc * (float)(zi * zj) * rinv;
            if (ee != 0.0f) atomicAdd(&y[idx_m[i]], ee);
        }
    };

    const int t = blockIdx.x * blockDim.x + tid;
    const int nthr = gridDim.x * blockDim.x;
    const int E4 = E >> 2;

    for (int g = t; g < E4; g += nthr) {
        const int4 vi = idx_i4[g];
        const int4 vj = idx_j4[g];
        const float4 r0 = r4[3 * g + 0];
        const float4 r1 = r4[3 * g + 1];
        const float4 r2 = r4[3 * g + 2];
        edge1(vi.x, vj.x, r0.x * r0.x + r0.y * r0.y + r0.z * r0.z);
        edge1(vi.y, vj.y, r0.w * r0.w + r1.x * r1.x + r1.y * r1.y);
        edge1(vi.z, vj.z, r1.z * r1.z + r1.w * r1.w + r2.x * r2.x);
        edge1(vi.w, vj.w, r2.y * r2.y + r2.z * r2.z + r2.w * r2.w);
    }

    // tail (E % 4 != 0 — not hit for this benchmark but kept for generality)
    for (int e = (E4 << 2) + t; e < E; e += nthr) {
        const float x  = r_ij[3 * e + 0];
        const float yy = r_ij[3 * e + 1];
        const float zz = r_ij[3 * e + 2];
        edge1(idx_i[e], idx_j[e], x * x + yy * yy + zz * zz);
    }
}

// ===========================================================================
// Fallback (no workspace): gather Z/idx_m directly, pow per edge, LDS bins
// ===========================================================================
__global__ __launch_bounds__(256) void zbl_edge_kernel_nows(
    const float* __restrict__ r_ij,
    const int* __restrict__ idx_i,
    const int* __restrict__ idx_j,
    const float* __restrict__ Z,
    const int* __restrict__ idx_m,
    const float* __restrict__ adiv,
    const float* __restrict__ apow,
    const float* __restrict__ a_vector,
    const float* __restrict__ c_vector,
    float* __restrict__ y, int E)
{
    __shared__ float bins[NUM_MOL];
    for (int b = threadIdx.x; b < NUM_MOL; b += blockDim.x) bins[b] = 0.0f;
    __syncthreads();

    const float sp_apow = softplus_f(apow[0]);
    const float sp_adiv = softplus_f(adiv[0]);
    const float sa0 = softplus_f(a_vector[0]);
    const float sa1 = softplus_f(a_vector[1]);
    const float sa2 = softplus_f(a_vector[2]);
    const float sa3 = softplus_f(a_vector[3]);
    float c0 = softplus_f(c_vector[0]);
    float c1 = softplus_f(c_vector[1]);
    float c2 = softplus_f(c_vector[2]);
    float c3 = softplus_f(c_vector[3]);
    const float cs = fabsf(c0) + fabsf(c1) + fabsf(c2) + fabsf(c3);
    const float cinv = 1.0f / cs;
    c0 *= cinv; c1 *= cinv; c2 *= cinv; c3 *= cinv;

    const int stride = gridDim.x * blockDim.x;
    for (int e = blockIdx.x * blockDim.x + threadIdx.x; e < E; e += stride) {
        const int i = idx_i[e];
        const int j = idx_j[e];
        const float zi = Z[i];
        const float zj = Z[j];
        const float x  = r_ij[3 * e + 0];
        const float yy = r_ij[3 * e + 1];
        const float zz = r_ij[3 * e + 2];
        const float d = sqrtf(x * x + yy * yy + zz * zz);

        const float u = d * (1.0f / RCUT);
        const float u3 = u * u * u;
        float fc = 1.0f + u3 * (-10.0f + u * (15.0f - 6.0f * u));
        fc = (d < RCUT) ? fc : 0.0f;

        const float a = (__powf(zi, sp_apow) + __powf(zj, sp_apow)) * sp_adiv;
        const float ad = a * d;
        const float ft = c0 * __expf(-sa0 * ad) + c1 * __expf(-sa1 * ad)
                       + c2 * __expf(-sa2 * ad) + c3 * __expf(-sa3 * ad);

        const float ee = KEHALF * ft * fc * zi * zj / d;
        if (ee != 0.0f) atomicAdd(&bins[idx_m[i]], ee);
    }

    __syncthreads();
    for (int b = threadIdx.x; b < NUM_MOL; b += blockDim.x) {
        const float v = bins[b];
        if (v != 0.0f) atomicAdd(&y[b], v);
    }
}

extern "C" void kernel_launch(void* const* d_in, const int* in_sizes, int n_in,
                              void* d_out, int out_size, void* d_ws, size_t ws_size,
                              hipStream_t stream) {
    // setup_inputs order: Z, r_ij, idx_i, idx_j, idx_m, adiv, apow, a_vector, c_vector
    const float* Z        = (const float*)d_in[0];
    const float* r_ij     = (const float*)d_in[1];
    const int*   idx_i    = (const int*)d_in[2];
    const int*   idx_j    = (const int*)d_in[3];
    const int*   idx_m    = (const int*)d_in[4];
    const float* adiv     = (const float*)d_in[5];
    const float* apow     = (const float*)d_in[6];
    const float* a_vector = (const float*)d_in[7];
    const float* c_vector = (const float*)d_in[8];
    float* y = (float*)d_out;

    const int N = in_sizes[0];
    const int E = in_sizes[1] / 3;

    // d_out is poisoned 0xAA before every launch -> zero it (graph-safe memset node)
    hipMemsetAsync(y, 0, (size_t)out_size * sizeof(float), stream);

    const size_t ws_need = 1024 + (size_t)N + 16;
    if (ws_size >= ws_need) {
        float* zptab_g = (float*)d_ws;
        unsigned char* zu8 = (unsigned char*)d_ws + 1024;
        zbl_prep<<<(N / 4 + 255) / 256 + 1, 256, 0, stream>>>(
            Z, apow, adiv, zptab_g, zu8, N);
        // 512 blocks x 1024 threads: 2 blocks/CU (65.3KB LDS) = 32 waves/CU
        zbl_edge_split<<<512, 1024, 0, stream>>>(
            (const float4*)r_ij, (const int4*)idx_i, (const int4*)idx_j,
            idx_i, idx_j, r_ij, zu8, zptab_g, idx_m,
            a_vector, c_vector, y, N, E);
    } else {
        zbl_edge_kernel_nows<<<2048, 256, 0, stream>>>(r_ij, idx_i, idx_j, Z, idx_m,
                                                       adiv, apow, a_vector, c_vector, y, E);
    }
}